// Round 7
// baseline (289.164 us; speedup 1.0000x reference)
//
#include <hip/hip_runtime.h>

typedef __bf16 bf16x8 __attribute__((ext_vector_type(8)));
typedef float f32x4 __attribute__((ext_vector_type(4)));
typedef unsigned short u16;

#define D_MODEL 1024
#define SEQ     2048
#define BATCH   4
#define NH      16
#define DH      64

// Q is stored prescaled by 1/sqrt(Dh) * log2(e); attn uses exp2 directly.
#define QSCALE 0.18033688011f

// both-sides bank swizzle for the epilogue bounce buffer: injects byte bits
// [9:7] (per-lane-distinct, non-bank) into bank bits [6:4]. Keeps [3:0].
#define SWZ(b) ((b) ^ ((((b) >> 8) & 3) << 5) ^ ((((b) >> 7) & 1) << 4))

static __device__ __forceinline__ u16 f2bf(float f) {
    union { float f; unsigned u; } v; v.f = f;
    unsigned r = v.u + 0x7FFF + ((v.u >> 16) & 1);  // RNE
    return (u16)(r >> 16);
}
static __device__ __forceinline__ void storeC(u16* C, size_t off, float v) { C[off] = f2bf(v); }
static __device__ __forceinline__ void storeC(float* C, size_t off, float v) { C[off] = v; }

// async global->LDS, 16 B per lane; lds must be wave-uniform base
static __device__ __forceinline__ void async_ld16(u16* lds, const u16* g) {
    __builtin_amdgcn_global_load_lds(
        (const __attribute__((address_space(1))) unsigned int*)g,
        (__attribute__((address_space(3))) unsigned int*)lds, 16, 0, 0);
}

// ---------------------------------------------------------------------------
// Merged prepass (single launch):
//   blocks [0,4096)          : fp32 -> bf16 convert of x (8 elems/thread)
//   blocks [4096,7168)       : transpose qkv_w [1024][3072] -> [3072][1024]
//   blocks [7168,8192)       : transpose out_w [1024][1024] -> [1024][1024]
// ---------------------------------------------------------------------------
__global__ __launch_bounds__(256) void prepass(
    const float* __restrict__ x,     u16* __restrict__ xb,
    const float* __restrict__ qkv_w, u16* __restrict__ Wqkv_t,
    const float* __restrict__ out_w, u16* __restrict__ Wout_t) {
    __shared__ float tile[32][33];
    int bid = blockIdx.x, tid = threadIdx.x;

    if (bid < 4096) {                       // cvt_bf16 part
        size_t i = ((size_t)bid * 256 + tid) * 8;
        float4 a = *(const float4*)(x + i);
        float4 b = *(const float4*)(x + i + 4);
        u16 t[8] = {f2bf(a.x), f2bf(a.y), f2bf(a.z), f2bf(a.w),
                    f2bf(b.x), f2bf(b.y), f2bf(b.z), f2bf(b.w)};
        *(uint4*)(xb + i) = *(uint4*)t;
        return;
    }

    const float* in; u16* out; int n0, k0, N;
    if (bid < 7168) {                       // qkv_w transpose
        int bb = bid - 4096;                // [0,3072)
        n0 = (bb % 96) * 32; k0 = (bb / 96) * 32;
        in = qkv_w; out = Wqkv_t; N = 3 * D_MODEL;
    } else {                                // out_w transpose
        int bb = bid - 7168;                // [0,1024)
        n0 = (bb & 31) * 32; k0 = (bb >> 5) * 32;
        in = out_w; out = Wout_t; N = D_MODEL;
    }
    int tx = tid & 31, ty = tid >> 5;
    for (int i = ty; i < 32; i += 8)
        tile[i][tx] = in[(size_t)(k0 + i) * N + n0 + tx];
    __syncthreads();
    for (int i = ty; i < 32; i += 8)
        out[(size_t)(n0 + i) * D_MODEL + k0 + tx] = f2bf(tile[tx][i]);
}

// ---------------------------------------------------------------------------
// Generic GEMM: C[M,N] = A @ Bt^T + bias.  128x128 tile, 4 waves.
// 2-phase counted schedule (verified R2): double-buffered LDS; prefetch next
// tile before computing current; one __syncthreads per K-iteration.
// ---------------------------------------------------------------------------
template <typename CT>
__global__ __launch_bounds__(256) void gemm_bt(
    const u16* __restrict__ A, int lda,
    const u16* __restrict__ Bt, int ldb,
    const float* __restrict__ bias,
    CT* __restrict__ C, int ldc, int K) {
    __shared__ u16 As[2][128 * 64];
    __shared__ u16 Bs[2][128 * 64];
    int m0 = blockIdx.x * 128, n0 = blockIdx.y * 128;
    int tid = threadIdx.x;
    int w = tid >> 6, lane = tid & 63, l15 = lane & 15, g = lane >> 4;
    int wm = (w & 1) * 64, wn = (w >> 1) * 64;
    int srow = w * 8 + (lane >> 3);
    int sk8  = lane & 7;

    auto stage = [&](int buf, int kt) {
        #pragma unroll
        for (int p = 0; p < 4; ++p) {
            int row = p * 32 + srow;
            int k8 = sk8 ^ (row & 7);
            async_ld16(&As[buf][p * 2048 + w * 512],
                       A + (size_t)(m0 + row) * lda + kt + k8 * 8);
            async_ld16(&Bs[buf][p * 2048 + w * 512],
                       Bt + (size_t)(n0 + row) * ldb + kt + k8 * 8);
        }
    };

    f32x4 acc[4][4] = {};

    stage(0, 0);
    __syncthreads();
    for (int kt = 0; kt < K; kt += 64) {
        int cur = (kt >> 6) & 1;
        if (kt + 64 < K) stage(cur ^ 1, kt + 64);   // prefetch next tile
        #pragma unroll
        for (int kk = 0; kk < 2; ++kk) {
            bf16x8 af[4], bf_[4];
            int s8 = ((kk << 2) | g) ^ (l15 & 7);
            #pragma unroll
            for (int i = 0; i < 4; ++i) {
                af[i]  = *(const bf16x8*)&As[cur][(wm + i * 16 + l15) * 64 + s8 * 8];
                bf_[i] = *(const bf16x8*)&Bs[cur][(wn + i * 16 + l15) * 64 + s8 * 8];
            }
            #pragma unroll
            for (int i = 0; i < 4; ++i)
                #pragma unroll
                for (int j = 0; j < 4; ++j)
                    acc[i][j] = __builtin_amdgcn_mfma_f32_16x16x32_bf16(
                        af[i], bf_[j], acc[i][j], 0, 0, 0);
        }
        __syncthreads();   // drains vmcnt: next buffer staged for everyone
    }
    #pragma unroll
    for (int j = 0; j < 4; ++j) {
        int n = n0 + wn + j * 16 + l15;
        float bv = bias[n];
        #pragma unroll
        for (int i = 0; i < 4; ++i) {
            int mbase = m0 + wm + i * 16 + g * 4;
            #pragma unroll
            for (int r = 0; r < 4; ++r)
                storeC(C, (size_t)(mbase + r) * ldc + n, acc[i][j][r] + bv);
        }
    }
}

// ---------------------------------------------------------------------------
// QKV GEMM (128x128, 2-phase counted schedule) with scatter epilogue:
//   Q columns  -> Qd [M][1024] dense bf16, PRESCALED by QSCALE (direct store)
//   K/V columns -> pkK/pkV fragment-packed via SWIZZLED LDS-BOUNCE:
//     scatter f2bf(acc+bias) into LDS at SWZ(packed byte offset) (kills the
//     8-way bank conflict of the K scatter), then copy to global fully
//     coalesced (uint4 from SWZ(granule) -> linear global). Values are
//     bitwise-identical to the direct scatter; only the store path changes.
// region is uniform per block (n0 128-aligned, regions 1024-aligned).
// ---------------------------------------------------------------------------
__global__ __launch_bounds__(256) void gemm_qkv(
    const u16* __restrict__ A,            // xb [M][1024]
    const u16* __restrict__ Bt,           // Wqkv_t [3072][1024]
    const float* __restrict__ bias,       // [3072]
    u16* __restrict__ Qd, u16* __restrict__ pkK, u16* __restrict__ pkV) {
    __shared__ u16 As[2][128 * 64];
    __shared__ u16 Bs[2][128 * 64];
    const int K = D_MODEL;
    int m0 = blockIdx.x * 128, n0 = blockIdx.y * 128;
    int tid = threadIdx.x;
    int w = tid >> 6, lane = tid & 63, l15 = lane & 15, g = lane >> 4;
    int wm = (w & 1) * 64, wn = (w >> 1) * 64;
    int srow = w * 8 + (lane >> 3);
    int sk8  = lane & 7;

    auto stage = [&](int buf, int kt) {
        #pragma unroll
        for (int p = 0; p < 4; ++p) {
            int row = p * 32 + srow;
            int k8 = sk8 ^ (row & 7);
            async_ld16(&As[buf][p * 2048 + w * 512],
                       A + (size_t)(m0 + row) * K + kt + k8 * 8);
            async_ld16(&Bs[buf][p * 2048 + w * 512],
                       Bt + (size_t)(n0 + row) * K + kt + k8 * 8);
        }
    };

    f32x4 acc[4][4] = {};

    stage(0, 0);
    __syncthreads();
    for (int kt = 0; kt < K; kt += 64) {
        int cur = (kt >> 6) & 1;
        if (kt + 64 < K) stage(cur ^ 1, kt + 64);   // prefetch next tile
        #pragma unroll
        for (int kk = 0; kk < 2; ++kk) {
            bf16x8 af[4], bf_[4];
            int s8 = ((kk << 2) | g) ^ (l15 & 7);
            #pragma unroll
            for (int i = 0; i < 4; ++i) {
                af[i]  = *(const bf16x8*)&As[cur][(wm + i * 16 + l15) * 64 + s8 * 8];
                bf_[i] = *(const bf16x8*)&Bs[cur][(wn + i * 16 + l15) * 64 + s8 * 8];
            }
            #pragma unroll
            for (int i = 0; i < 4; ++i)
                #pragma unroll
                for (int j = 0; j < 4; ++j)
                    acc[i][j] = __builtin_amdgcn_mfma_f32_16x16x32_bf16(
                        af[i], bf_[j], acc[i][j], 0, 0, 0);
        }
        __syncthreads();   // drains vmcnt: next buffer staged for everyone
        // after the LAST iteration this barrier also makes As/Bs reusable
    }

    int region = n0 >> 10;                 // block-uniform
    if (region == 0) {
        // ---- dense Q store, prescaled (32B-sector granular, acceptable) ----
        #pragma unroll
        for (int j = 0; j < 4; ++j) {
            int n = n0 + wn + j * 16 + l15;
            float bv = bias[n];
            int hd = n & 1023;
            #pragma unroll
            for (int i = 0; i < 4; ++i) {
                #pragma unroll
                for (int r = 0; r < 4; ++r) {
                    int m = m0 + wm + i * 16 + g * 4 + r;
                    Qd[(size_t)m * 1024 + hd] =
                        f2bf((acc[i][j][r] + bv) * QSCALE);
                }
            }
        }
        return;
    }

    // ---- K/V: swizzled LDS-bounce into packed layout, coalesced copy ----
    char* lds = (char*)As;                 // 32 KB scratch (main loop done)
    int h0 = (n0 & 1023) >> 6;             // first head col-group of tile
    int t0 = (m0 & 2047) >> 6;             // first t-chunk of tile
    int bb = m0 >> 11;                     // batch (m0 never crosses)

    if (region == 1) {
        // K: lk from row, kk/gk/jk from col; b16 writes at SWZ'd offsets
        #pragma unroll
        for (int j = 0; j < 4; ++j) {
            int dn = wn + j * 16 + l15;    // col within tile [0,128)
            float bv = bias[n0 + dn];
            int hp = dn >> 6, d = dn & 63;
            int kk = d >> 5, gk = (d >> 3) & 3, jk = d & 7;
            #pragma unroll
            for (int i = 0; i < 4; ++i) {
                #pragma unroll
                for (int r = 0; r < 4; ++r) {
                    int mm = wm + i * 16 + g * 4 + r;   // row within tile
                    int tp = mm >> 6, kap = mm & 63;
                    int nb = kap >> 4, lk = kap & 15;
                    int o = (((nb * 2 + kk) * 64 + gk * 16 + lk) * 8 + jk) * 2;
                    *(u16*)(lds + (hp * 2 + tp) * 8192 + SWZ(o)) =
                        f2bf(acc[i][j][r] + bv);
                }
            }
        }
    } else {
        // V: r-values consecutive -> pack 4 into one 8B write (SWZ keeps
        // bits [3:0], so 8B alignment is preserved)
        #pragma unroll
        for (int j = 0; j < 4; ++j) {
            int dn = wn + j * 16 + l15;
            float bv = bias[n0 + dn];
            int hp = dn >> 6, d = dn & 63;
            int nb = d >> 4, lv = d & 15;
            #pragma unroll
            for (int i = 0; i < 4; ++i) {
                int mmb = wm + i * 16 + g * 4;          // r-base row
                int tp = mmb >> 6, kapb = mmb & 63;
                int kk = kapb >> 5, gv = (kapb >> 3) & 3, jvb = kapb & 7;
                union { u16 q[4]; unsigned long long ll; } p4;
                #pragma unroll
                for (int r = 0; r < 4; ++r)
                    p4.q[r] = f2bf(acc[i][j][r] + bv);
                int o = (((nb * 2 + kk) * 64 + gv * 16 + lv) * 8 + jvb) * 2;
                *(unsigned long long*)(lds + (hp * 2 + tp) * 8192 + SWZ(o)) =
                    p4.ll;
            }
        }
    }
    __syncthreads();
    u16* pk = (region == 1) ? pkK : pkV;
    #pragma unroll
    for (int c = 0; c < 4; ++c) {
        int hp = c >> 1, tp = c & 1;
        u16* dst = pk + ((size_t)((bb * 16 + h0 + hp) * 32) + t0 + tp) * 4096;
        int o0 = tid * 32, o1 = tid * 32 + 16;
        uint4 v0 = *(uint4*)(lds + c * 8192 + SWZ(o0));
        uint4 v1 = *(uint4*)(lds + c * 8192 + SWZ(o1));
        *(uint4*)&dst[tid * 16]     = v0;
        *(uint4*)&dst[tid * 16 + 8] = v1;
    }
}

// ---------------------------------------------------------------------------
// Flash attention, causal, no-max softmax, wave-split-K + CAUSAL PAIRING:
// block handles q-tiles {31-p, p} (uniform 33 tiles/block -> no drain tail).
// K/V fragments stream from packed buffers (perfectly coalesced b128 loads).
// 4 waves = (2 q-halves) x (2 K-parities); zero barriers in K-loop; O/l
// merged across parities via LDS. In/out: dense Qd (written in-place).
// Q comes prescaled by QSCALE -> p = exp2(s) directly (no per-elem mul).
// Diag handled via flag on the last parity tile.
// T14 register double-buffer: next K/V tile's 16 b128 loads issue BEFORE
// computing the current tile (statically named bufs A/B -> no scratch).
// grid = (B*NH, 16).
// ---------------------------------------------------------------------------
__global__ __launch_bounds__(256) void attn_flash(
    u16* __restrict__ Qd, const u16* __restrict__ pkK,
    const u16* __restrict__ pkV) {
    __shared__ __align__(16) char smemraw[18432 + 256];
    u16 (*Pt)[32][72] = (u16(*)[32][72])smemraw;    // per-wave [32 q][72]
    float* Om = (float*)smemraw;                     // post-loop: [64 q][65]
    float* Lm = (float*)(smemraw + 18432);           // post-loop: [64 q]

    int bh = blockIdx.x, b = bh >> 4, h = bh & 15;
    int tid = threadIdx.x;
    int w = tid >> 6, lane = tid & 63, l15 = lane & 15, g = lane >> 4;
    int wq = w >> 1, wk = w & 1;

    const u16* Kb = pkK + (size_t)bh * 32 * 4096;
    const u16* Vb = pkV + (size_t)bh * 32 * 4096;
    u16* Qbase = Qd + (size_t)b * SEQ * 1024 + h * DH;

    int qts[2] = {31 - (int)blockIdx.y, (int)blockIdx.y};

    #pragma unroll
    for (int qi = 0; qi < 2; ++qi) {
        int qt = qts[qi];
        int q0 = qt * 64;

        // Q fragments (already prescaled by QSCALE in gemm_qkv)
        bf16x8 qfrag[2][2];
        #pragma unroll
        for (int st = 0; st < 2; ++st) {
            const u16* qp = Qbase + (size_t)(q0 + wq * 32 + st * 16 + l15) * 1024 + g * 8;
            qfrag[st][0] = *(const bf16x8*)qp;
            qfrag[st][1] = *(const bf16x8*)(qp + 32);
        }

        f32x4 o[2][4] = {};
        float lsum[2][4] = {};

        auto loadKV = [&](int t, bf16x8 (&kf)[4][2], bf16x8 (&vf)[4][2]) {
            const u16* kt = Kb + t * 4096;
            const u16* vt = Vb + t * 4096;
            #pragma unroll
            for (int nb = 0; nb < 4; ++nb) {
                #pragma unroll
                for (int kk = 0; kk < 2; ++kk) {
                    kf[nb][kk] = *(const bf16x8*)(kt + ((nb * 2 + kk) * 64 + lane) * 8);
                    vf[nb][kk] = *(const bf16x8*)(vt + ((nb * 2 + kk) * 64 + lane) * 8);
                }
            }
        };

        auto compute = [&](int t, bool diag,
                           bf16x8 (&kf)[4][2], bf16x8 (&vf)[4][2]) {
            int k0 = t * 64;
            #pragma unroll
            for (int st = 0; st < 2; ++st) {
                f32x4 s[4] = {};
                #pragma unroll
                for (int nb = 0; nb < 4; ++nb)
                    #pragma unroll
                    for (int kk = 0; kk < 2; ++kk)
                        s[nb] = __builtin_amdgcn_mfma_f32_16x16x32_bf16(
                            qfrag[st][kk], kf[nb][kk], s[nb], 0, 0, 0);

                #pragma unroll
                for (int r = 0; r < 4; ++r) {
                    int qg = q0 + wq * 32 + st * 16 + g * 4 + r;
                    #pragma unroll
                    for (int nb = 0; nb < 4; ++nb) {
                        float p = __builtin_amdgcn_exp2f(s[nb][r]);
                        if (diag && (k0 + nb * 16 + l15) > qg) p = 0.f;
                        lsum[st][r] += p;
                        Pt[w][st * 16 + g * 4 + r][nb * 16 + l15] =
                            (u16)(__float_as_uint(p) >> 16);
                    }
                }

                #pragma unroll
                for (int kk = 0; kk < 2; ++kk) {
                    bf16x8 aP = *(const bf16x8*)&Pt[w][st * 16 + l15][kk * 32 + g * 8];
                    #pragma unroll
                    for (int nb = 0; nb < 4; ++nb)
                        o[st][nb] = __builtin_amdgcn_mfma_f32_16x16x32_bf16(
                            aP, vf[nb][kk], o[st][nb], 0, 0, 0);
                }
            }
        };

        // software-pipelined t-loop: issue loads for t+2 before computing t
        {
            bf16x8 kfA[4][2], vfA[4][2], kfB[4][2], vfB[4][2];
            int t = wk;
            if (t <= qt) {
                loadKV(t, kfA, vfA);
                for (;;) {
                    int tn = t + 2;
                    bool hn = tn <= qt;
                    if (hn) loadKV(tn, kfB, vfB);
                    compute(t, t == qt, kfA, vfA);
                    if (!hn) break;
                    t = tn;
                    tn = t + 2;
                    bool hn2 = tn <= qt;
                    if (hn2) loadKV(tn, kfA, vfA);
                    compute(t, t == qt, kfB, vfB);
                    if (!hn2) break;
                    t = tn;
                }
            }
        }

        // per-wave row-sum butterfly (16 cols across 16 lanes)
        #pragma unroll
        for (int msk = 1; msk < 16; msk <<= 1)
            #pragma unroll
            for (int st = 0; st < 2; ++st)
                #pragma unroll
                for (int r = 0; r < 4; ++r)
                    lsum[st][r] += __shfl_xor(lsum[st][r], msk, 64);

        // merge the two K-parities via LDS (Om/Lm alias the dead Pt)
        __syncthreads();
        if (wk == 0) {
            #pragma unroll
            for (int st = 0; st < 2; ++st)
                #pragma unroll
                for (int r = 0; r < 4; ++r) {
                    int qrow = wq * 32 + st * 16 + g * 4 + r;
                    if (l15 == 0) Lm[qrow] = lsum[st][r];
                    #pragma unroll
                    for (int nb = 0; nb < 4; ++nb)
                        Om[qrow * 65 + nb * 16 + l15] = o[st][nb][r];
                }
        }
        __syncthreads();
        if (wk == 1) {
            #pragma unroll
            for (int st = 0; st < 2; ++st)
                #pragma unroll
                for (int r = 0; r < 4; ++r) {
                    int qrow = wq * 32 + st * 16 + g * 4 + r;
                    float inv = 1.f / (lsum[st][r] + Lm[qrow]);
                    u16* op = Qbase + (size_t)(q0 + qrow) * 1024;
                    #pragma unroll
                    for (int nb = 0; nb < 4; ++nb) {
                        float val = (o[st][nb][r] + Om[qrow * 65 + nb * 16 + l15]) * inv;
                        op[nb * 16 + l15] = f2bf(val);
                    }
                }
        }
        __syncthreads();   // protect Pt before next q-tile reuses it
    }
}

// ---------------------------------------------------------------------------
extern "C" void kernel_launch(void* const* d_in, const int* in_sizes, int n_in,
                              void* d_out, int out_size, void* d_ws, size_t ws_size,
                              hipStream_t stream) {
    const float* x     = (const float*)d_in[0];
    const float* qkv_w = (const float*)d_in[1];
    const float* qkv_b = (const float*)d_in[2];
    const float* out_w = (const float*)d_in[3];
    const float* out_b = (const float*)d_in[4];
    float* out = (float*)d_out;

    const int M = BATCH * SEQ;                             // 8192
    u16* Qd     = (u16*)d_ws;                              // [M][1024]      16.8 MB
    u16* pkK    = Qd  + (size_t)M * D_MODEL;               // [64][32][4096] 16.8 MB
    u16* pkV    = pkK + (size_t)64 * 32 * 4096;            //                16.8 MB
    u16* xb     = pkV + (size_t)64 * 32 * 4096;            // [M][1024]      16.8 MB
    u16* Wqkv_t = xb  + (size_t)M * D_MODEL;               // [3072][1024]    6.3 MB
    u16* Wout_t = Wqkv_t + (size_t)3 * D_MODEL * D_MODEL;  // [1024][1024]    2.1 MB

    // merged prepass: cvt + both weight transposes in one launch
    prepass<<<dim3(8192), 256, 0, stream>>>(x, xb, qkv_w, Wqkv_t, out_w, Wout_t);

    // QKV projection with fused scatter into Qd / packed K / packed V
    gemm_qkv<<<dim3(M / 128, 3 * D_MODEL / 128), 256, 0, stream>>>(
        xb, Wqkv_t, qkv_b, Qd, pkK, pkV);

    // paired causal flash attention (in-place on Qd)
    attn_flash<<<dim3(BATCH * NH, SEQ / 64 / 2), 256, 0, stream>>>(Qd, pkK, pkV);

    // output projection
    gemm_bt<float><<<dim3(M / 128, D_MODEL / 128), 256, 0, stream>>>(
        Qd, D_MODEL, Wout_t, D_MODEL, out_b, out, D_MODEL, D_MODEL);
}

// Round 8
// 228.511 us; speedup vs baseline: 1.2654x; 1.2654x over previous
//
#include <hip/hip_runtime.h>

typedef __bf16 bf16x8 __attribute__((ext_vector_type(8)));
typedef float f32x4 __attribute__((ext_vector_type(4)));
typedef unsigned short u16;

#define D_MODEL 1024
#define SEQ     2048
#define BATCH   4
#define NH      16
#define DH      64

// Q is stored prescaled by 1/sqrt(Dh) * log2(e); attn uses exp2 directly.
#define QSCALE 0.18033688011f

// both-sides bank swizzle for the epilogue bounce buffer: injects byte bits
// [9:7] (per-lane-distinct, non-bank) into bank bits [6:4]. Keeps [3:0].
#define SWZ(b) ((b) ^ ((((b) >> 8) & 3) << 5) ^ ((((b) >> 7) & 1) << 4))

static __device__ __forceinline__ u16 f2bf(float f) {
    union { float f; unsigned u; } v; v.f = f;
    unsigned r = v.u + 0x7FFF + ((v.u >> 16) & 1);  // RNE
    return (u16)(r >> 16);
}
static __device__ __forceinline__ void storeC(u16* C, size_t off, float v) { C[off] = f2bf(v); }
static __device__ __forceinline__ void storeC(float* C, size_t off, float v) { C[off] = v; }

// async global->LDS, 16 B per lane; lds must be wave-uniform base
static __device__ __forceinline__ void async_ld16(u16* lds, const u16* g) {
    __builtin_amdgcn_global_load_lds(
        (const __attribute__((address_space(1))) unsigned int*)g,
        (__attribute__((address_space(3))) unsigned int*)lds, 16, 0, 0);
}

// ---------------------------------------------------------------------------
// Merged prepass (single launch):
//   blocks [0,4096)          : fp32 -> bf16 convert of x (8 elems/thread)
//   blocks [4096,7168)       : transpose qkv_w [1024][3072] -> [3072][1024]
//   blocks [7168,8192)       : transpose out_w [1024][1024] -> [1024][1024]
// ---------------------------------------------------------------------------
__global__ __launch_bounds__(256) void prepass(
    const float* __restrict__ x,     u16* __restrict__ xb,
    const float* __restrict__ qkv_w, u16* __restrict__ Wqkv_t,
    const float* __restrict__ out_w, u16* __restrict__ Wout_t) {
    __shared__ float tile[32][33];
    int bid = blockIdx.x, tid = threadIdx.x;

    if (bid < 4096) {                       // cvt_bf16 part
        size_t i = ((size_t)bid * 256 + tid) * 8;
        float4 a = *(const float4*)(x + i);
        float4 b = *(const float4*)(x + i + 4);
        u16 t[8] = {f2bf(a.x), f2bf(a.y), f2bf(a.z), f2bf(a.w),
                    f2bf(b.x), f2bf(b.y), f2bf(b.z), f2bf(b.w)};
        *(uint4*)(xb + i) = *(uint4*)t;
        return;
    }

    const float* in; u16* out; int n0, k0, N;
    if (bid < 7168) {                       // qkv_w transpose
        int bb = bid - 4096;                // [0,3072)
        n0 = (bb % 96) * 32; k0 = (bb / 96) * 32;
        in = qkv_w; out = Wqkv_t; N = 3 * D_MODEL;
    } else {                                // out_w transpose
        int bb = bid - 7168;                // [0,1024)
        n0 = (bb & 31) * 32; k0 = (bb >> 5) * 32;
        in = out_w; out = Wout_t; N = D_MODEL;
    }
    int tx = tid & 31, ty = tid >> 5;
    for (int i = ty; i < 32; i += 8)
        tile[i][tx] = in[(size_t)(k0 + i) * N + n0 + tx];
    __syncthreads();
    for (int i = ty; i < 32; i += 8)
        out[(size_t)(n0 + i) * D_MODEL + k0 + tx] = f2bf(tile[tx][i]);
}

// ---------------------------------------------------------------------------
// Generic GEMM: C[M,N] = A @ Bt^T + bias.  128x128 tile, 4 waves.
// 2-phase counted schedule (verified R2): double-buffered LDS; prefetch next
// tile before computing current; one __syncthreads per K-iteration.
// ---------------------------------------------------------------------------
template <typename CT>
__global__ __launch_bounds__(256) void gemm_bt(
    const u16* __restrict__ A, int lda,
    const u16* __restrict__ Bt, int ldb,
    const float* __restrict__ bias,
    CT* __restrict__ C, int ldc, int K) {
    __shared__ u16 As[2][128 * 64];
    __shared__ u16 Bs[2][128 * 64];
    int m0 = blockIdx.x * 128, n0 = blockIdx.y * 128;
    int tid = threadIdx.x;
    int w = tid >> 6, lane = tid & 63, l15 = lane & 15, g = lane >> 4;
    int wm = (w & 1) * 64, wn = (w >> 1) * 64;
    int srow = w * 8 + (lane >> 3);
    int sk8  = lane & 7;

    auto stage = [&](int buf, int kt) {
        #pragma unroll
        for (int p = 0; p < 4; ++p) {
            int row = p * 32 + srow;
            int k8 = sk8 ^ (row & 7);
            async_ld16(&As[buf][p * 2048 + w * 512],
                       A + (size_t)(m0 + row) * lda + kt + k8 * 8);
            async_ld16(&Bs[buf][p * 2048 + w * 512],
                       Bt + (size_t)(n0 + row) * ldb + kt + k8 * 8);
        }
    };

    f32x4 acc[4][4] = {};

    stage(0, 0);
    __syncthreads();
    for (int kt = 0; kt < K; kt += 64) {
        int cur = (kt >> 6) & 1;
        if (kt + 64 < K) stage(cur ^ 1, kt + 64);   // prefetch next tile
        #pragma unroll
        for (int kk = 0; kk < 2; ++kk) {
            bf16x8 af[4], bf_[4];
            int s8 = ((kk << 2) | g) ^ (l15 & 7);
            #pragma unroll
            for (int i = 0; i < 4; ++i) {
                af[i]  = *(const bf16x8*)&As[cur][(wm + i * 16 + l15) * 64 + s8 * 8];
                bf_[i] = *(const bf16x8*)&Bs[cur][(wn + i * 16 + l15) * 64 + s8 * 8];
            }
            #pragma unroll
            for (int i = 0; i < 4; ++i)
                #pragma unroll
                for (int j = 0; j < 4; ++j)
                    acc[i][j] = __builtin_amdgcn_mfma_f32_16x16x32_bf16(
                        af[i], bf_[j], acc[i][j], 0, 0, 0);
        }
        __syncthreads();   // drains vmcnt: next buffer staged for everyone
    }
    #pragma unroll
    for (int j = 0; j < 4; ++j) {
        int n = n0 + wn + j * 16 + l15;
        float bv = bias[n];
        #pragma unroll
        for (int i = 0; i < 4; ++i) {
            int mbase = m0 + wm + i * 16 + g * 4;
            #pragma unroll
            for (int r = 0; r < 4; ++r)
                storeC(C, (size_t)(mbase + r) * ldc + n, acc[i][j][r] + bv);
        }
    }
}

// ---------------------------------------------------------------------------
// QKV GEMM (128x128, 2-phase counted schedule) with scatter epilogue:
//   Q columns  -> Qd [M][1024] dense bf16, PRESCALED by QSCALE (direct store)
//   K/V columns -> pkK/pkV fragment-packed via SWIZZLED LDS-BOUNCE:
//     scatter f2bf(acc+bias) into LDS at SWZ(packed byte offset) (kills the
//     8-way bank conflict of the K scatter), then copy to global fully
//     coalesced (uint4 from SWZ(granule) -> linear global). Values are
//     bitwise-identical to the direct scatter; only the store path changes.
// region is uniform per block (n0 128-aligned, regions 1024-aligned).
// ---------------------------------------------------------------------------
__global__ __launch_bounds__(256) void gemm_qkv(
    const u16* __restrict__ A,            // xb [M][1024]
    const u16* __restrict__ Bt,           // Wqkv_t [3072][1024]
    const float* __restrict__ bias,       // [3072]
    u16* __restrict__ Qd, u16* __restrict__ pkK, u16* __restrict__ pkV) {
    __shared__ u16 As[2][128 * 64];
    __shared__ u16 Bs[2][128 * 64];
    const int K = D_MODEL;
    int m0 = blockIdx.x * 128, n0 = blockIdx.y * 128;
    int tid = threadIdx.x;
    int w = tid >> 6, lane = tid & 63, l15 = lane & 15, g = lane >> 4;
    int wm = (w & 1) * 64, wn = (w >> 1) * 64;
    int srow = w * 8 + (lane >> 3);
    int sk8  = lane & 7;

    auto stage = [&](int buf, int kt) {
        #pragma unroll
        for (int p = 0; p < 4; ++p) {
            int row = p * 32 + srow;
            int k8 = sk8 ^ (row & 7);
            async_ld16(&As[buf][p * 2048 + w * 512],
                       A + (size_t)(m0 + row) * K + kt + k8 * 8);
            async_ld16(&Bs[buf][p * 2048 + w * 512],
                       Bt + (size_t)(n0 + row) * K + kt + k8 * 8);
        }
    };

    f32x4 acc[4][4] = {};

    stage(0, 0);
    __syncthreads();
    for (int kt = 0; kt < K; kt += 64) {
        int cur = (kt >> 6) & 1;
        if (kt + 64 < K) stage(cur ^ 1, kt + 64);   // prefetch next tile
        #pragma unroll
        for (int kk = 0; kk < 2; ++kk) {
            bf16x8 af[4], bf_[4];
            int s8 = ((kk << 2) | g) ^ (l15 & 7);
            #pragma unroll
            for (int i = 0; i < 4; ++i) {
                af[i]  = *(const bf16x8*)&As[cur][(wm + i * 16 + l15) * 64 + s8 * 8];
                bf_[i] = *(const bf16x8*)&Bs[cur][(wn + i * 16 + l15) * 64 + s8 * 8];
            }
            #pragma unroll
            for (int i = 0; i < 4; ++i)
                #pragma unroll
                for (int j = 0; j < 4; ++j)
                    acc[i][j] = __builtin_amdgcn_mfma_f32_16x16x32_bf16(
                        af[i], bf_[j], acc[i][j], 0, 0, 0);
        }
        __syncthreads();   // drains vmcnt: next buffer staged for everyone
        // after the LAST iteration this barrier also makes As/Bs reusable
    }

    int region = n0 >> 10;                 // block-uniform
    if (region == 0) {
        // ---- dense Q store, prescaled (32B-sector granular, acceptable) ----
        #pragma unroll
        for (int j = 0; j < 4; ++j) {
            int n = n0 + wn + j * 16 + l15;
            float bv = bias[n];
            int hd = n & 1023;
            #pragma unroll
            for (int i = 0; i < 4; ++i) {
                #pragma unroll
                for (int r = 0; r < 4; ++r) {
                    int m = m0 + wm + i * 16 + g * 4 + r;
                    Qd[(size_t)m * 1024 + hd] =
                        f2bf((acc[i][j][r] + bv) * QSCALE);
                }
            }
        }
        return;
    }

    // ---- K/V: swizzled LDS-bounce into packed layout, coalesced copy ----
    char* lds = (char*)As;                 // 32 KB scratch (main loop done)
    int h0 = (n0 & 1023) >> 6;             // first head col-group of tile
    int t0 = (m0 & 2047) >> 6;             // first t-chunk of tile
    int bb = m0 >> 11;                     // batch (m0 never crosses)

    if (region == 1) {
        // K: lk from row, kk/gk/jk from col; b16 writes at SWZ'd offsets
        #pragma unroll
        for (int j = 0; j < 4; ++j) {
            int dn = wn + j * 16 + l15;    // col within tile [0,128)
            float bv = bias[n0 + dn];
            int hp = dn >> 6, d = dn & 63;
            int kk = d >> 5, gk = (d >> 3) & 3, jk = d & 7;
            #pragma unroll
            for (int i = 0; i < 4; ++i) {
                #pragma unroll
                for (int r = 0; r < 4; ++r) {
                    int mm = wm + i * 16 + g * 4 + r;   // row within tile
                    int tp = mm >> 6, kap = mm & 63;
                    int nb = kap >> 4, lk = kap & 15;
                    int o = (((nb * 2 + kk) * 64 + gk * 16 + lk) * 8 + jk) * 2;
                    *(u16*)(lds + (hp * 2 + tp) * 8192 + SWZ(o)) =
                        f2bf(acc[i][j][r] + bv);
                }
            }
        }
    } else {
        // V: r-values consecutive -> pack 4 into one 8B write (SWZ keeps
        // bits [3:0], so 8B alignment is preserved)
        #pragma unroll
        for (int j = 0; j < 4; ++j) {
            int dn = wn + j * 16 + l15;
            float bv = bias[n0 + dn];
            int hp = dn >> 6, d = dn & 63;
            int nb = d >> 4, lv = d & 15;
            #pragma unroll
            for (int i = 0; i < 4; ++i) {
                int mmb = wm + i * 16 + g * 4;          // r-base row
                int tp = mmb >> 6, kapb = mmb & 63;
                int kk = kapb >> 5, gv = (kapb >> 3) & 3, jvb = kapb & 7;
                union { u16 q[4]; unsigned long long ll; } p4;
                #pragma unroll
                for (int r = 0; r < 4; ++r)
                    p4.q[r] = f2bf(acc[i][j][r] + bv);
                int o = (((nb * 2 + kk) * 64 + gv * 16 + lv) * 8 + jvb) * 2;
                *(unsigned long long*)(lds + (hp * 2 + tp) * 8192 + SWZ(o)) =
                    p4.ll;
            }
        }
    }
    __syncthreads();
    u16* pk = (region == 1) ? pkK : pkV;
    #pragma unroll
    for (int c = 0; c < 4; ++c) {
        int hp = c >> 1, tp = c & 1;
        u16* dst = pk + ((size_t)((bb * 16 + h0 + hp) * 32) + t0 + tp) * 4096;
        int o0 = tid * 32, o1 = tid * 32 + 16;
        uint4 v0 = *(uint4*)(lds + c * 8192 + SWZ(o0));
        uint4 v1 = *(uint4*)(lds + c * 8192 + SWZ(o1));
        *(uint4*)&dst[tid * 16]     = v0;
        *(uint4*)&dst[tid * 16 + 8] = v1;
    }
}

// ---------------------------------------------------------------------------
// Flash attention, causal, no-max softmax — TLP-maximized 2-wave blocks:
// one q-tile per block, each wave owns 32 q-rows over the FULL K range.
// No split-K, no merge phase, ZERO barriers, per-wave Pt in LDS (9.2 KB).
// grid = (B*NH, 32) with qt = 31 - blockIdx.y (largest tiles dispatch first
// -> LPT load balancing of the variable causal work).
// K/V fragments stream from packed buffers (coalesced b128 loads; latency
// hidden by high block residency -- R7 showed dur ~ 1/occupancy).
// Q comes prescaled by QSCALE -> p = exp2(s) directly.
// Diag-split: mask ops only on the final (diagonal) tile.
// ---------------------------------------------------------------------------
__global__ __launch_bounds__(128) void attn_flash(
    u16* __restrict__ Qd, const u16* __restrict__ pkK,
    const u16* __restrict__ pkV) {
    __shared__ __align__(16) u16 Pt[2][32][72];     // per-wave [32 q][72]

    int bh = blockIdx.x, b = bh >> 4, h = bh & 15;
    int tid = threadIdx.x;
    int w = tid >> 6, lane = tid & 63, l15 = lane & 15, g = lane >> 4;

    const u16* Kb = pkK + (size_t)bh * 32 * 4096;
    const u16* Vb = pkV + (size_t)bh * 32 * 4096;
    u16* Qbase = Qd + (size_t)b * SEQ * 1024 + h * DH;

    int qt = 31 - (int)blockIdx.y;      // big tiles first (LPT)
    int q0 = qt * 64;

    // Q fragments (already prescaled by QSCALE in gemm_qkv)
    bf16x8 qfrag[2][2];
    #pragma unroll
    for (int st = 0; st < 2; ++st) {
        const u16* qp = Qbase + (size_t)(q0 + w * 32 + st * 16 + l15) * 1024 + g * 8;
        qfrag[st][0] = *(const bf16x8*)qp;
        qfrag[st][1] = *(const bf16x8*)(qp + 32);
    }

    f32x4 o[2][4] = {};
    float lsum[2][4] = {};

    auto ktile = [&](int t, bool diag) {
        const u16* kt = Kb + t * 4096;
        const u16* vt = Vb + t * 4096;
        bf16x8 kf[4][2], vf[4][2];
        #pragma unroll
        for (int nb = 0; nb < 4; ++nb) {
            #pragma unroll
            for (int kk = 0; kk < 2; ++kk) {
                kf[nb][kk] = *(const bf16x8*)(kt + ((nb * 2 + kk) * 64 + lane) * 8);
                vf[nb][kk] = *(const bf16x8*)(vt + ((nb * 2 + kk) * 64 + lane) * 8);
            }
        }
        int k0 = t * 64;

        #pragma unroll
        for (int st = 0; st < 2; ++st) {
            f32x4 s[4] = {};
            #pragma unroll
            for (int nb = 0; nb < 4; ++nb)
                #pragma unroll
                for (int kk = 0; kk < 2; ++kk)
                    s[nb] = __builtin_amdgcn_mfma_f32_16x16x32_bf16(
                        qfrag[st][kk], kf[nb][kk], s[nb], 0, 0, 0);

            #pragma unroll
            for (int r = 0; r < 4; ++r) {
                int qg = q0 + w * 32 + st * 16 + g * 4 + r;
                #pragma unroll
                for (int nb = 0; nb < 4; ++nb) {
                    float p = __builtin_amdgcn_exp2f(s[nb][r]);
                    if (diag && (k0 + nb * 16 + l15) > qg) p = 0.f;
                    lsum[st][r] += p;
                    Pt[w][st * 16 + g * 4 + r][nb * 16 + l15] =
                        (u16)(__float_as_uint(p) >> 16);
                }
            }

            #pragma unroll
            for (int kk = 0; kk < 2; ++kk) {
                bf16x8 aP = *(const bf16x8*)&Pt[w][st * 16 + l15][kk * 32 + g * 8];
                #pragma unroll
                for (int nb = 0; nb < 4; ++nb)
                    o[st][nb] = __builtin_amdgcn_mfma_f32_16x16x32_bf16(
                        aP, vf[nb][kk], o[st][nb], 0, 0, 0);
            }
        }
    };

    // mask-free main loop; diagonal tile handled once, with mask
    for (int t = 0; t < qt; ++t) ktile(t, false);
    ktile(qt, true);

    // per-wave row-sum butterfly (16 cols across 16 lanes)
    #pragma unroll
    for (int msk = 1; msk < 16; msk <<= 1)
        #pragma unroll
        for (int st = 0; st < 2; ++st)
            #pragma unroll
            for (int r = 0; r < 4; ++r)
                lsum[st][r] += __shfl_xor(lsum[st][r], msk, 64);

    // direct normalize + store (wave owns its rows fully; no merge)
    #pragma unroll
    for (int st = 0; st < 2; ++st)
        #pragma unroll
        for (int r = 0; r < 4; ++r) {
            int qrow = w * 32 + st * 16 + g * 4 + r;
            float inv = 1.f / lsum[st][r];
            u16* op = Qbase + (size_t)(q0 + qrow) * 1024;
            #pragma unroll
            for (int nb = 0; nb < 4; ++nb)
                op[nb * 16 + l15] = f2bf(o[st][nb][r] * inv);
        }
}

// ---------------------------------------------------------------------------
extern "C" void kernel_launch(void* const* d_in, const int* in_sizes, int n_in,
                              void* d_out, int out_size, void* d_ws, size_t ws_size,
                              hipStream_t stream) {
    const float* x     = (const float*)d_in[0];
    const float* qkv_w = (const float*)d_in[1];
    const float* qkv_b = (const float*)d_in[2];
    const float* out_w = (const float*)d_in[3];
    const float* out_b = (const float*)d_in[4];
    float* out = (float*)d_out;

    const int M = BATCH * SEQ;                             // 8192
    u16* Qd     = (u16*)d_ws;                              // [M][1024]      16.8 MB
    u16* pkK    = Qd  + (size_t)M * D_MODEL;               // [64][32][4096] 16.8 MB
    u16* pkV    = pkK + (size_t)64 * 32 * 4096;            //                16.8 MB
    u16* xb     = pkV + (size_t)64 * 32 * 4096;            // [M][1024]      16.8 MB
    u16* Wqkv_t = xb  + (size_t)M * D_MODEL;               // [3072][1024]    6.3 MB
    u16* Wout_t = Wqkv_t + (size_t)3 * D_MODEL * D_MODEL;  // [1024][1024]    2.1 MB

    // merged prepass: cvt + both weight transposes in one launch
    prepass<<<dim3(8192), 256, 0, stream>>>(x, xb, qkv_w, Wqkv_t, out_w, Wout_t);

    // QKV projection with fused scatter into Qd / packed K / packed V
    gemm_qkv<<<dim3(M / 128, 3 * D_MODEL / 128), 256, 0, stream>>>(
        xb, Wqkv_t, qkv_b, Qd, pkK, pkV);

    // causal flash attention, 2-wave blocks, one q-tile each, LPT order
    attn_flash<<<dim3(BATCH * NH, SEQ / 64), 128, 0, stream>>>(Qd, pkK, pkV);

    // output projection
    gemm_bt<float><<<dim3(M / 128, D_MODEL / 128), 256, 0, stream>>>(
        Qd, D_MODEL, Wout_t, D_MODEL, out_b, out, D_MODEL, D_MODEL);
}